// Round 13
// baseline (364.474 us; speedup 1.0000x reference)
//
#include <hip/hip_runtime.h>
#include <hip/hip_bf16.h>
#include <hip/hip_cooperative_groups.h>

namespace cg = cooperative_groups;

// MMD loss via bf16 MFMA Gram matrix — R13: cooperative fusion, hardened.
// R12 failed with unwritten output => hipLaunchCooperativeKernel never ran
// (likely VGPR>170 without min-waves bound => 2 blocks/CU co-residency < 768).
// Fixes: __launch_bounds__(256,3) enforces 3 blocks/CU (R11 gemm = 68 VGPR under
// this bound), and the launch return code is checked with a full fallback to the
// R11 3-kernel path (known-passing, 108us).
//
// Zc layout (R7): Zc[ck][row][32], stored quad = q ^ ((row>>1)&3); each mfma
// fragment = one contiguous coalesced 1KB block.
// Lessons: R4 no per-block fences in hot loops; R5 no occupancy forcing past
// register budget; R6 no scattered vector loads; R3/R7 barrier-free K-loop.
//
// ws: [0,4MiB) bf16 Zc; float norms_part[4][8192] (128KiB); float norms[8192];
//     double dpart[768]; float fpart[2080].

#define NSIG  5
#define CKS   262144                 // chunk stride in ushorts: 8192 rows * 32
#define NBLK2 2080                   // 64-supergrid triangle
#define GRID  768                    // 3 blocks/CU x 256 CUs, enforced by launch_bounds

typedef __attribute__((ext_vector_type(8))) short short8;
typedef __attribute__((ext_vector_type(4))) float floatx4;

// ---- prep job: job = s(1)|b(2)|cgh(2)|pq(2), 128 jobs; 2 K-chunks per job ----
__device__ __forceinline__ void prep_job(const int job, const int t,
                                         const float* __restrict__ x,
                                         const float* __restrict__ y,
                                         ushort* __restrict__ Zc,
                                         float* __restrict__ norms_part,
                                         ushort* tile) {
    const int s   = job >> 6;
    const int b   = (job >> 4) & 3;
    const int cgh = (job >> 2) & 3;      // chunk pair: chunks 2*cgh, 2*cgh+1
    const int pq  = job & 3;
    const float* src = s ? y : x;
    const int p0 = pq << 8;
    const int n0 = (s << 12) + (b << 10) + p0;
    const int row = n0 + t;
    const int sw = (row >> 1) & 3;
    float ns = 0.f;

    for (int h = 0; h < 2; ++h) {
        const int cgi = (cgh << 1) + h;
        __syncthreads();                 // tile reusable (prev pass reads done)
        // phase 1: each wave inst = 64 lanes x float4 = 1KB contiguous
#pragma unroll
        for (int it = 0; it < 8; ++it) {
            const int g = (it << 8) + t;
            const int cl = g >> 6;
            const int pf = (g & 63) << 2;
            const float4 v = *(const float4*)(src +
                ((size_t)((b << 8) + (cgi << 5) + cl) << 10) + p0 + pf);
            const __hip_bfloat16 h0 = __float2bfloat16(v.x);
            const __hip_bfloat16 h1 = __float2bfloat16(v.y);
            const __hip_bfloat16 h2 = __float2bfloat16(v.z);
            const __hip_bfloat16 h3 = __float2bfloat16(v.w);
            const uint u0 = (uint)(*(const ushort*)&h0) | ((uint)(*(const ushort*)&h1) << 16);
            const uint u1 = (uint)(*(const ushort*)&h2) | ((uint)(*(const ushort*)&h3) << 16);
            *(uint2*)(&tile[(cl << 8) + pf]) = make_uint2(u0, u1);
        }
        __syncthreads();
        // phase 2: thread t = row; pack 64B chunk-row, 4 dwordx4 stores
        uint pk[16];
#pragma unroll
        for (int c = 0; c < 32; ++c) {
            const ushort uv = tile[(c << 8) + t];
            const float f = __bfloat162float(*(const __hip_bfloat16*)&uv);
            ns = fmaf(f, f, ns);
            if ((c & 1) == 0) pk[c >> 1] = (uint)uv;
            else              pk[c >> 1] |= ((uint)uv) << 16;
        }
        ushort* dst = Zc + (size_t)cgi * CKS + ((size_t)row << 5);
#pragma unroll
        for (int qq = 0; qq < 4; ++qq) {
            const int sq = qq ^ sw;
            *(uint4*)(dst + (sq << 3)) = make_uint4(pk[4*qq], pk[4*qq+1], pk[4*qq+2], pk[4*qq+3]);
        }
    }
    norms_part[(cgh << 13) + row] = ns;  // unique (cgh,row), non-atomic
}

// ---- gemm tile: returns per-lane lsum (sign applied; 0 if inactive) ----
__device__ __forceinline__ float gemm_tile(const int lin, const int w, const int l,
                                           const ushort* __restrict__ Zc,
                                           const float* __restrict__ norms,
                                           const float* __restrict__ sigmas) {
    int p = (int)((-4.0f + sqrtf(16.0f + 128.0f * (float)lin)) * (1.0f / 64.0f));
    p = p < 0 ? 0 : (p > 7 ? 7 : p);
    while (p < 7 && 32 * (p + 1) * (p + 1) + 4 * (p + 1) <= lin) ++p;
    while (p > 0 && 32 * p * p + 4 * p > lin) --p;
    const int o = lin - (32 * p * p + 4 * p);
    int c = 7;
#pragma unroll
    for (int cc = 7; cc >= 1; --cc) {
        const int Q = cc * (8 * p + 1) + (cc * (cc - 1)) / 2;
        if (o < Q) c = cc - 1;
    }
    const int Qc = c * (8 * p + 1) + (c * (c - 1)) / 2;
    const int tj2 = 8 * p + c;
    const int ti2 = o - Qc;

    const int ti = (ti2 << 1) + (w >> 1);
    const int tj = (tj2 << 1) + (w & 1);
    if (ti > tj) return 0.f;
    const bool diag = (ti == tj);
    const int i0 = ti << 6, j0 = tj << 6;
    const int m = l & 15, q = l >> 4;

    int offA[4], offB[4];
#pragma unroll
    for (int f = 0; f < 4; ++f) {
        const int ra = i0 + (f << 4) + m;
        offA[f] = (ra << 5) + (((q ^ ((ra >> 1) & 3))) << 3);
        const int rb = j0 + (f << 4) + m;
        offB[f] = (rb << 5) + (((q ^ ((rb >> 1) & 3))) << 3);
    }

    floatx4 accf[4][4];
#pragma unroll
    for (int fi = 0; fi < 4; ++fi)
#pragma unroll
        for (int fj = 0; fj < 4; ++fj) accf[fi][fj] = (floatx4){0.f, 0.f, 0.f, 0.f};

    short8 curA[4], curB[4], nxtA[4], nxtB[4];
#pragma unroll
    for (int f = 0; f < 4; ++f) {
        curA[f] = *(const short8*)(Zc + offA[f]);
        curB[f] = *(const short8*)(Zc + offB[f]);
    }
#pragma unroll
    for (int ck = 0; ck < 8; ++ck) {
        if (ck < 7) {
            const size_t ko = (size_t)(ck + 1) * CKS;
#pragma unroll
            for (int f = 0; f < 4; ++f) {
                nxtA[f] = *(const short8*)(Zc + ko + offA[f]);
                nxtB[f] = *(const short8*)(Zc + ko + offB[f]);
            }
        }
#pragma unroll
        for (int fi = 0; fi < 4; ++fi)
#pragma unroll
            for (int fj = 0; fj < 4; ++fj)
                accf[fi][fj] = __builtin_amdgcn_mfma_f32_16x16x32_bf16(curA[fi], curB[fj], accf[fi][fj], 0, 0, 0);
        if (ck < 7) {
#pragma unroll
            for (int f = 0; f < 4; ++f) { curA[f] = nxtA[f]; curB[f] = nxtB[f]; }
        }
    }

    float c2[NSIG];
#pragma unroll
    for (int k = 0; k < NSIG; ++k) c2[k] = (-0.5f / sigmas[k]) * 1.44269504f;
    const float sgn2 = ((ti < 64) == (tj < 64)) ? 2.f : -2.f;

#pragma unroll
    for (int fi = 0; fi < 4; ++fi) {
        const floatx4 ni4 = *(const floatx4*)(norms + i0 + (fi << 4) + (q << 2));
#pragma unroll
        for (int fj = 0; fj < 4; ++fj) {
            const float njs = norms[j0 + (fj << 4) + m];
#pragma unroll
            for (int v = 0; v < 4; ++v) {
                float d = fmaf(-2.f, accf[fi][fj][v], ni4[v] + njs);
                d = fmaxf(d, 0.f);
                if (diag) {
                    const int dif = ((fi - fj) << 4) + ((q << 2) + v) - m;
                    d = (dif < 0) ? d : 3.0e9f;   // strictly-upper only
                }
                accf[fi][fj][v] = d;
            }
        }
    }

    float dmin = accf[0][0][0];
#pragma unroll
    for (int fi = 0; fi < 4; ++fi)
#pragma unroll
        for (int fj = 0; fj < 4; ++fj)
#pragma unroll
            for (int v = 0; v < 4; ++v) dmin = fminf(dmin, accf[fi][fj][v]);
#pragma unroll
    for (int off = 1; off < 64; off <<= 1) dmin = fminf(dmin, __shfl_xor(dmin, off, 64));

    float lsum = 0.f;
#pragma unroll
    for (int k = 0; k < NSIG; ++k) {
        if (c2[k] * dmin >= -126.f) {   // wave-uniform skip iff all exps underflow
#pragma unroll
            for (int fi = 0; fi < 4; ++fi)
#pragma unroll
                for (int fj = 0; fj < 4; ++fj)
#pragma unroll
                    for (int v = 0; v < 4; ++v)
                        lsum += __builtin_amdgcn_exp2f(c2[k] * accf[fi][fj][v]);
        }
    }
    return lsum * sgn2;
}

// ================= fused cooperative kernel =================
__global__ __launch_bounds__(256, 3) void fused_kernel(
    const float* __restrict__ x, const float* __restrict__ y,
    const float* __restrict__ sigmas,
    ushort* __restrict__ Zc, float* __restrict__ norms_part,
    float* __restrict__ norms, double* __restrict__ partials,
    float* __restrict__ out)
{
    cg::grid_group gg = cg::this_grid();
    const int t = threadIdx.x;
    const int bid = blockIdx.x;

    __shared__ ushort tile[32 * 256];   // 16 KB (phase A)
    __shared__ float wsum[4];
    __shared__ double sh[256];

    if (bid < 128) prep_job(bid, t, x, y, Zc, norms_part, tile);
    gg.sync();

    if (bid < 32) {
        const int row = (bid << 8) + t;
        float s = 0.f;
#pragma unroll
        for (int g = 0; g < 4; ++g) s += norms_part[(g << 13) + row];
        norms[row] = s;
    }
    gg.sync();

    const int w = t >> 6, l = t & 63;
    double blockAcc = 0.0;
    for (int lin = bid; lin < NBLK2; lin += GRID) {
        float lsum = gemm_tile(lin, w, l, Zc, norms, sigmas);
#pragma unroll
        for (int off = 32; off > 0; off >>= 1) lsum += __shfl_down(lsum, off, 64);
        if (l == 0) wsum[w] = lsum;
        __syncthreads();
        if (t == 0) blockAcc += (double)(wsum[0] + wsum[1] + wsum[2] + wsum[3]);
        __syncthreads();
    }
    if (t == 0) partials[bid] = blockAcc;
    gg.sync();

    if (bid == 0) {
        double s = 0.0;
        for (int i = t; i < GRID; i += 256) s += partials[i];
        sh[t] = s;
        __syncthreads();
        for (int st = 128; st > 0; st >>= 1) {
            if (t < st) sh[t] += sh[t + st];
            __syncthreads();
        }
        if (t == 0) out[0] = (float)((sh[0] + 8192.0 * NSIG) * (1.0 / (4096.0 * 4096.0)));
    }
}

// ================= fallback path (R11 structure, proven) =================
__global__ __launch_bounds__(256) void prep_fb(const float* __restrict__ x,
                                               const float* __restrict__ y,
                                               ushort* __restrict__ Zc,
                                               float* __restrict__ norms_part) {
    __shared__ ushort tile[32 * 256];
    prep_job(blockIdx.x, threadIdx.x, x, y, Zc, norms_part, tile);
}

__global__ __launch_bounds__(256) void nred_fb(const float* __restrict__ norms_part,
                                               float* __restrict__ norms) {
    const int row = (blockIdx.x << 8) + threadIdx.x;
    float s = 0.f;
#pragma unroll
    for (int g = 0; g < 4; ++g) s += norms_part[(g << 13) + row];
    norms[row] = s;
}

__global__ __launch_bounds__(256, 3) void gemm_fb(const ushort* __restrict__ Zc,
                                                  const float* __restrict__ norms,
                                                  const float* __restrict__ sigmas,
                                                  float* __restrict__ partials) {
    __shared__ float wsum[4];
    const int t = threadIdx.x;
    const int w = t >> 6, l = t & 63;
    float lsum = gemm_tile(blockIdx.x, w, l, Zc, norms, sigmas);
#pragma unroll
    for (int off = 32; off > 0; off >>= 1) lsum += __shfl_down(lsum, off, 64);
    if (l == 0) wsum[w] = lsum;
    __syncthreads();
    if (t == 0) partials[blockIdx.x] = wsum[0] + wsum[1] + wsum[2] + wsum[3];
}

__global__ __launch_bounds__(256) void fin_fb(const float* __restrict__ partials,
                                              float* __restrict__ out) {
    __shared__ double sh[256];
    const int t = threadIdx.x;
    double s = 0.0;
    for (int i = t; i < NBLK2; i += 256) s += (double)partials[i];
    sh[t] = s;
    __syncthreads();
    for (int st = 128; st > 0; st >>= 1) {
        if (t < st) sh[t] += sh[t + st];
        __syncthreads();
    }
    if (t == 0) out[0] = (float)((sh[0] + 8192.0 * NSIG) * (1.0 / (4096.0 * 4096.0)));
}

extern "C" void kernel_launch(void* const* d_in, const int* in_sizes, int n_in,
                              void* d_out, int out_size, void* d_ws, size_t ws_size,
                              hipStream_t stream) {
    const float* x   = (const float*)d_in[0];
    const float* y   = (const float*)d_in[1];
    const float* sig = (const float*)d_in[2];

    ushort* Zc        = (ushort*)d_ws;                                         // 4 MiB
    float* norms_part = (float*)((char*)d_ws + (size_t)8192 * 256 * 2);        // 128 KiB
    float* norms      = (float*)((char*)norms_part + 4 * 8192 * sizeof(float));// 32 KiB
    double* dpart     = (double*)((char*)norms + 8192 * sizeof(float));        // 6 KiB
    float* fpart      = (float*)((char*)dpart + GRID * sizeof(double));        // 8.3 KiB
    float* out        = (float*)d_out;

    void* args[] = { (void*)&x, (void*)&y, (void*)&sig, (void*)&Zc,
                     (void*)&norms_part, (void*)&norms, (void*)&dpart, (void*)&out };
    hipError_t err = hipLaunchCooperativeKernel((const void*)fused_kernel,
                                                dim3(GRID), dim3(256), args, 0, stream);
    if (err != hipSuccess) {
        // proven R11-style path
        prep_fb<<<128, 256, 0, stream>>>(x, y, Zc, norms_part);
        nred_fb<<<32, 256, 0, stream>>>(norms_part, norms);
        gemm_fb<<<NBLK2, 256, 0, stream>>>(Zc, norms, sig, fpart);
        fin_fb<<<1, 256, 0, stream>>>(fpart, out);
    }
}

// Round 14
// 121.065 us; speedup vs baseline: 3.0106x; 3.0106x over previous
//
#include <hip/hip_runtime.h>
#include <hip/hip_bf16.h>

// MMD loss via bf16 MFMA Gram matrix — R14: 1-wave gemm blocks.
// R13 lessons: cooperative grid.sync = device fence x blocks x XCDs => 6x
// regression (coop dead); residual ~60us is harness-fixed (1 dispatch showed
// same residual) => optimize kernel-time sum only.
// R11 ledger: 13k cyc/wave-tile vs ~2k compute; 256-thread blocks put all 4
// waves in phase (bursty loads, correlated stalls). Fix: one 64x64 wave-tile
// per 64-thread block, no LDS/sync, per-wave partials, column-major triangle
// decode (consecutive blocks share B-tile even under %8 XCD striping).
//
// Zc layout (R7): Zc[ck][row][32], stored quad = q ^ ((row>>1)&3); each mfma
// fragment = one contiguous coalesced 1KB block.
// Lessons kept: R4 no fences in hot kernels; R5 no forced occupancy; R6 no
// scattered vector loads; R3/R7 barrier-staged K-loop plateaus at ~51us.
//
// ws: [0,4MiB) bf16 Zc; float norms_part[4][8192]; float norms[8192];
//     float partials[8256].

#define NSIG  5
#define CKS   262144                  // chunk stride in ushorts: 8192 rows * 32
#define NWT   8256                    // 128*129/2 wave-tiles

typedef __attribute__((ext_vector_type(8))) short short8;
typedef __attribute__((ext_vector_type(4))) float floatx4;

// ---- prep job (verified in R13): job = s(1)|b(2)|cgh(2)|pq(2), 128 jobs ----
__global__ __launch_bounds__(256) void prep_kernel(const float* __restrict__ x,
                                                   const float* __restrict__ y,
                                                   ushort* __restrict__ Zc,
                                                   float* __restrict__ norms_part) {
    __shared__ ushort tile[32 * 256];
    const int job = blockIdx.x, t = threadIdx.x;
    const int s   = job >> 6;
    const int b   = (job >> 4) & 3;
    const int cgh = (job >> 2) & 3;
    const int pq  = job & 3;
    const float* src = s ? y : x;
    const int p0 = pq << 8;
    const int n0 = (s << 12) + (b << 10) + p0;
    const int row = n0 + t;
    const int sw = (row >> 1) & 3;
    float ns = 0.f;

    for (int h = 0; h < 2; ++h) {
        const int cgi = (cgh << 1) + h;
        __syncthreads();
#pragma unroll
        for (int it = 0; it < 8; ++it) {
            const int g = (it << 8) + t;
            const int cl = g >> 6;
            const int pf = (g & 63) << 2;
            const float4 v = *(const float4*)(src +
                ((size_t)((b << 8) + (cgi << 5) + cl) << 10) + p0 + pf);
            const __hip_bfloat16 h0 = __float2bfloat16(v.x);
            const __hip_bfloat16 h1 = __float2bfloat16(v.y);
            const __hip_bfloat16 h2 = __float2bfloat16(v.z);
            const __hip_bfloat16 h3 = __float2bfloat16(v.w);
            const uint u0 = (uint)(*(const ushort*)&h0) | ((uint)(*(const ushort*)&h1) << 16);
            const uint u1 = (uint)(*(const ushort*)&h2) | ((uint)(*(const ushort*)&h3) << 16);
            *(uint2*)(&tile[(cl << 8) + pf]) = make_uint2(u0, u1);
        }
        __syncthreads();
        uint pk[16];
#pragma unroll
        for (int c = 0; c < 32; ++c) {
            const ushort uv = tile[(c << 8) + t];
            const float f = __bfloat162float(*(const __hip_bfloat16*)&uv);
            ns = fmaf(f, f, ns);
            if ((c & 1) == 0) pk[c >> 1] = (uint)uv;
            else              pk[c >> 1] |= ((uint)uv) << 16;
        }
        ushort* dst = Zc + (size_t)cgi * CKS + ((size_t)row << 5);
#pragma unroll
        for (int qq = 0; qq < 4; ++qq) {
            const int sq = qq ^ sw;
            *(uint4*)(dst + (sq << 3)) = make_uint4(pk[4*qq], pk[4*qq+1], pk[4*qq+2], pk[4*qq+3]);
        }
    }
    norms_part[(cgh << 13) + row] = ns;
}

__global__ __launch_bounds__(256) void nred_kernel(const float* __restrict__ norms_part,
                                                   float* __restrict__ norms) {
    const int row = (blockIdx.x << 8) + threadIdx.x;
    float s = 0.f;
#pragma unroll
    for (int g = 0; g < 4; ++g) s += norms_part[(g << 13) + row];
    norms[row] = s;
}

// ---- gemm: one 64x64 wave-tile per 64-thread block, barrier/LDS-free ----
__global__ __launch_bounds__(64) void gemm_epi(const ushort* __restrict__ Zc,
                                               const float* __restrict__ norms,
                                               const float* __restrict__ sigmas,
                                               float* __restrict__ partials) {
    const int l = threadIdx.x;
    const int lin = blockIdx.x;

    // column-major triangle decode: tj = column, ti = 0..tj
    int tj = (int)((sqrtf(8.f * (float)lin + 1.f) - 1.f) * 0.5f);
    tj = tj < 0 ? 0 : (tj > 127 ? 127 : tj);
    while (((tj + 1) * (tj + 2)) / 2 <= lin) ++tj;
    while ((tj * (tj + 1)) / 2 > lin) --tj;
    const int ti = lin - (tj * (tj + 1)) / 2;
    const bool diag = (ti == tj);

    const int i0 = ti << 6, j0 = tj << 6;
    const int m = l & 15, q = l >> 4;

    int offA[4], offB[4];
#pragma unroll
    for (int f = 0; f < 4; ++f) {
        const int ra = i0 + (f << 4) + m;
        offA[f] = (ra << 5) + (((q ^ ((ra >> 1) & 3))) << 3);
        const int rb = j0 + (f << 4) + m;
        offB[f] = (rb << 5) + (((q ^ ((rb >> 1) & 3))) << 3);
    }

    floatx4 accf[4][4];
#pragma unroll
    for (int fi = 0; fi < 4; ++fi)
#pragma unroll
        for (int fj = 0; fj < 4; ++fj) accf[fi][fj] = (floatx4){0.f, 0.f, 0.f, 0.f};

    short8 curA[4], curB[4], nxtA[4], nxtB[4];
#pragma unroll
    for (int f = 0; f < 4; ++f) {
        curA[f] = *(const short8*)(Zc + offA[f]);
        curB[f] = *(const short8*)(Zc + offB[f]);
    }

#pragma unroll
    for (int ck = 0; ck < 8; ++ck) {
        if (ck < 7) {
            const size_t ko = (size_t)(ck + 1) * CKS;
#pragma unroll
            for (int f = 0; f < 4; ++f) {
                nxtA[f] = *(const short8*)(Zc + ko + offA[f]);
                nxtB[f] = *(const short8*)(Zc + ko + offB[f]);
            }
        }
#pragma unroll
        for (int fi = 0; fi < 4; ++fi)
#pragma unroll
            for (int fj = 0; fj < 4; ++fj)
                accf[fi][fj] = __builtin_amdgcn_mfma_f32_16x16x32_bf16(curA[fi], curB[fj], accf[fi][fj], 0, 0, 0);
        if (ck < 7) {
#pragma unroll
            for (int f = 0; f < 4; ++f) { curA[f] = nxtA[f]; curB[f] = nxtB[f]; }
        }
    }

    float c2[NSIG];
#pragma unroll
    for (int k = 0; k < NSIG; ++k) c2[k] = (-0.5f / sigmas[k]) * 1.44269504f;
    const float sgn2 = ((ti < 64) == (tj < 64)) ? 2.f : -2.f;

#pragma unroll
    for (int fi = 0; fi < 4; ++fi) {
        const floatx4 ni4 = *(const floatx4*)(norms + i0 + (fi << 4) + (q << 2));
#pragma unroll
        for (int fj = 0; fj < 4; ++fj) {
            const float njs = norms[j0 + (fj << 4) + m];
#pragma unroll
            for (int v = 0; v < 4; ++v) {
                float d = fmaf(-2.f, accf[fi][fj][v], ni4[v] + njs);
                d = fmaxf(d, 0.f);
                if (diag) {
                    const int dif = ((fi - fj) << 4) + ((q << 2) + v) - m;
                    d = (dif < 0) ? d : 3.0e9f;   // strictly-upper only
                }
                accf[fi][fj][v] = d;
            }
        }
    }

    float dmin = accf[0][0][0];
#pragma unroll
    for (int fi = 0; fi < 4; ++fi)
#pragma unroll
        for (int fj = 0; fj < 4; ++fj)
#pragma unroll
            for (int v = 0; v < 4; ++v) dmin = fminf(dmin, accf[fi][fj][v]);
#pragma unroll
    for (int off = 1; off < 64; off <<= 1) dmin = fminf(dmin, __shfl_xor(dmin, off, 64));

    float lsum = 0.f;
#pragma unroll
    for (int k = 0; k < NSIG; ++k) {
        if (c2[k] * dmin >= -126.f) {    // wave-uniform skip iff all exps underflow
#pragma unroll
            for (int fi = 0; fi < 4; ++fi)
#pragma unroll
                for (int fj = 0; fj < 4; ++fj)
#pragma unroll
                    for (int v = 0; v < 4; ++v)
                        lsum += __builtin_amdgcn_exp2f(c2[k] * accf[fi][fj][v]);
        }
    }
    lsum *= sgn2;

#pragma unroll
    for (int off = 32; off > 0; off >>= 1) lsum += __shfl_down(lsum, off, 64);
    if (l == 0) partials[lin] = lsum;
}

__global__ __launch_bounds__(256) void fin_kernel(const float* __restrict__ partials,
                                                  float* __restrict__ out) {
    __shared__ double sh[256];
    const int t = threadIdx.x;
    double s = 0.0;
    for (int i = t; i < NWT; i += 256) s += (double)partials[i];
    sh[t] = s;
    __syncthreads();
    for (int st = 128; st > 0; st >>= 1) {
        if (t < st) sh[t] += sh[t + st];
        __syncthreads();
    }
    if (t == 0) out[0] = (float)((sh[0] + 8192.0 * NSIG) * (1.0 / (4096.0 * 4096.0)));
}

extern "C" void kernel_launch(void* const* d_in, const int* in_sizes, int n_in,
                              void* d_out, int out_size, void* d_ws, size_t ws_size,
                              hipStream_t stream) {
    const float* x   = (const float*)d_in[0];
    const float* y   = (const float*)d_in[1];
    const float* sig = (const float*)d_in[2];

    ushort* Zc        = (ushort*)d_ws;                                          // 4 MiB
    float* norms_part = (float*)((char*)d_ws + (size_t)8192 * 256 * 2);         // 128 KiB
    float* norms      = (float*)((char*)norms_part + 4 * 8192 * sizeof(float)); // 32 KiB
    float* partials   = (float*)((char*)norms + 8192 * sizeof(float));          // 33 KiB
    float* out        = (float*)d_out;

    prep_kernel<<<128, 256, 0, stream>>>(x, y, Zc, norms_part);
    nred_kernel<<<32, 256, 0, stream>>>(norms_part, norms);
    gemm_epi<<<NWT, 64, 0, stream>>>(Zc, norms, sig, partials);
    fin_kernel<<<1, 256, 0, stream>>>(partials, out);
}